// Round 1
// baseline (904.619 us; speedup 1.0000x reference)
//
#include <hip/hip_runtime.h>
#include <stdint.h>

static constexpr float EPS = 1e-5f;

__device__ __forceinline__ float bf2f(unsigned short u){
  union { unsigned int i; float f; } v; v.i = ((unsigned int)u) << 16; return v.f;
}
__device__ __forceinline__ unsigned short f2bf(float f){
  union { float f; unsigned int i; } v; v.f = f;
  unsigned int x = v.i;
  x += 0x7fffu + ((x >> 16) & 1u);   // round-to-nearest-even
  return (unsigned short)(x >> 16);
}

// ---------------- graph build: degree, prefix-scan, CSR scatter ----------------
__global__ void k_deg(const int* __restrict__ col, int* __restrict__ indeg, int N, int E){
  int e = blockIdx.x * 256 + threadIdx.x;
  if (e < E){
    unsigned c = (unsigned)col[e];
    if (c < (unsigned)N) atomicAdd(&indeg[c], 1);
  }
}

__global__ void k_blocksum(const int* __restrict__ indeg, int* __restrict__ bsum, int N){
  __shared__ int sm[256];
  int i = blockIdx.x * 256 + threadIdx.x;
  sm[threadIdx.x] = (i < N) ? indeg[i] : 0;
  __syncthreads();
  for (int d = 128; d > 0; d >>= 1){
    if (threadIdx.x < d) sm[threadIdx.x] += sm[threadIdx.x + d];
    __syncthreads();
  }
  if (threadIdx.x == 0) bsum[blockIdx.x] = sm[0];
}

__global__ void k_scan_bsum(int* bsum, int nb){
  if (threadIdx.x == 0 && blockIdx.x == 0){
    int acc = 0;
    for (int b = 0; b < nb; b++){ int v = bsum[b]; bsum[b] = acc; acc += v; }
  }
}

__global__ void k_scan_node(const int* __restrict__ indeg, const int* __restrict__ bsum,
                            int* __restrict__ offs, int* __restrict__ cursor,
                            float* __restrict__ dinv, int N){
  __shared__ int sm[256];
  int i = blockIdx.x * 256 + threadIdx.x;
  int v = (i < N) ? indeg[i] : 0;
  sm[threadIdx.x] = v;
  __syncthreads();
  for (int d = 1; d < 256; d <<= 1){
    int t = (threadIdx.x >= d) ? sm[threadIdx.x - d] : 0;
    __syncthreads();
    sm[threadIdx.x] += t;
    __syncthreads();
  }
  if (i < N){
    int o = bsum[blockIdx.x] + sm[threadIdx.x] - v;   // exclusive
    offs[i] = o; cursor[i] = o;
    dinv[i] = rsqrtf((float)(v + 1));                 // deg = indeg + self-loop
  }
}

__global__ void k_scatter(const int* __restrict__ row, const int* __restrict__ col,
                          int* __restrict__ cursor, int* __restrict__ csr, int N, int E){
  int e = blockIdx.x * 256 + threadIdx.x;
  if (e < E){
    unsigned c = (unsigned)col[e];
    if (c < (unsigned)N){
      int p = atomicAdd(&cursor[c], 1);
      unsigned r = (unsigned)row[e];
      csr[p] = (r < (unsigned)N) ? (int)r : 0;
    }
  }
}

// ---------------- propagate s = P x  (fp32, 128-dim) ----------------
__global__ __launch_bounds__(128) void k_prop_x(const float* __restrict__ x, const int* __restrict__ csr,
                                                const int* __restrict__ offs, const int* __restrict__ indeg,
                                                const float* __restrict__ dinv, float* __restrict__ s, int N){
  int i = blockIdx.x;
  int c = threadIdx.x;
  float di = dinv[i];
  float acc = di * x[(size_t)i*128 + c];   // self-loop (one dinv applied at end)
  int base = offs[i], cnt = indeg[i];
  for (int e = 0; e < cnt; e++){
    int r = csr[base + e];
    acc += dinv[r] * x[(size_t)r*128 + c];
  }
  s[(size_t)i*128 + c] = di * acc;
}

// ---------------- z = s @ W1_all + b1   (N x 128) @ (128 x 512), bf16 out -------------
__global__ __launch_bounds__(256) void k_mm1(const float* __restrict__ s, const float* __restrict__ W,
                                             const float* __restrict__ b, unsigned short* __restrict__ z, int N){
  __shared__ float sl[16 * 128];
  int n0 = blockIdx.x * 16;
  for (int t = threadIdx.x; t < 16 * 128; t += 256){
    int nn = t >> 7, kk = t & 127;
    int n = n0 + nn;
    sl[t] = (n < N) ? s[(size_t)n * 128 + kk] : 0.f;
  }
  __syncthreads();
  int c0 = threadIdx.x, c1 = threadIdx.x + 256;
  const float* Wa = W + (size_t)(c0 >> 7) * 16384 + (c0 & 127);
  const float* Wb = W + (size_t)(c1 >> 7) * 16384 + (c1 & 127);
  float acc0[16], acc1[16];
  #pragma unroll
  for (int nn = 0; nn < 16; nn++){ acc0[nn] = 0.f; acc1[nn] = 0.f; }
  for (int k = 0; k < 128; k += 4){
    float wa0 = Wa[(k+0)*128], wa1 = Wa[(k+1)*128], wa2 = Wa[(k+2)*128], wa3 = Wa[(k+3)*128];
    float wb0 = Wb[(k+0)*128], wb1 = Wb[(k+1)*128], wb2 = Wb[(k+2)*128], wb3 = Wb[(k+3)*128];
    #pragma unroll
    for (int nn = 0; nn < 16; nn++){
      float4 sv = *(const float4*)&sl[nn*128 + k];
      acc0[nn] += sv.x*wa0 + sv.y*wa1 + sv.z*wa2 + sv.w*wa3;
      acc1[nn] += sv.x*wb0 + sv.y*wb1 + sv.z*wb2 + sv.w*wb3;
    }
  }
  float bb0 = b[c0], bb1 = b[c1];
  for (int nn = 0; nn < 16; nn++){
    int n = n0 + nn;
    if (n < N){
      z[(size_t)n*512 + c0] = f2bf(acc0[nn] + bb0);
      z[(size_t)n*512 + c1] = f2bf(acc1[nn] + bb1);
    }
  }
}

// ---------------- per-column sum / sumsq over bf16 (N x 512) ----------------
__global__ void k_stats(const unsigned short* __restrict__ z, float* __restrict__ ssum,
                        float* __restrict__ ssq, int N){
  int col = blockIdx.x * 256 + threadIdx.x;       // gridDim.x == 2
  float s = 0.f, q = 0.f;
  for (int n = blockIdx.y; n < N; n += gridDim.y){
    float v = bf2f(z[(size_t)n*512 + col]);
    s += v; q += v * v;
  }
  atomicAdd(&ssum[col], s);
  atomicAdd(&ssq[col], q);
}

__global__ void k_bnfix(const float* __restrict__ ssum, const float* __restrict__ ssq,
                        const float* __restrict__ gamma, const float* __restrict__ beta,
                        float* __restrict__ scale, float* __restrict__ shift, int N){
  int c = blockIdx.x * 256 + threadIdx.x;
  if (c < 512){
    float mean = ssum[c] / (float)N;
    float var  = ssq[c] / (float)N - mean * mean;
    float rstd = rsqrtf(var + EPS);
    float sc = rstd * gamma[c];
    scale[c] = sc;
    shift[c] = beta[c] - mean * sc;
  }
}

// ---------------- h = prelu(BN(z)) elementwise, bf16 in/out ----------------
__global__ void k_h(const unsigned short* __restrict__ z, const float* __restrict__ scale,
                    const float* __restrict__ shift, const float* __restrict__ alpha_p,
                    unsigned short* __restrict__ h, int total4){
  float alpha = alpha_p[0];
  int idx = blockIdx.x * 256 + threadIdx.x;
  int stride = gridDim.x * 256;
  for (; idx < total4; idx += stride){
    ushort4 u = ((const ushort4*)z)[idx];
    int c4 = idx & 127;                         // 512/4 groups per row
    float4 sc = ((const float4*)scale)[c4];
    float4 sh = ((const float4*)shift)[c4];
    float a0 = bf2f(u.x)*sc.x + sh.x; a0 = a0 > 0.f ? a0 : alpha*a0;
    float a1 = bf2f(u.y)*sc.y + sh.y; a1 = a1 > 0.f ? a1 : alpha*a1;
    float a2 = bf2f(u.z)*sc.z + sh.z; a2 = a2 > 0.f ? a2 : alpha*a2;
    float a3 = bf2f(u.w)*sc.w + sh.w; a3 = a3 > 0.f ? a3 : alpha*a3;
    ushort4 o; o.x = f2bf(a0); o.y = f2bf(a1); o.z = f2bf(a2); o.w = f2bf(a3);
    ((ushort4*)h)[idx] = o;
  }
}

// ---------------- t = P h  (bf16 512-dim gather) ----------------
__global__ __launch_bounds__(256) void k_prop_h(const unsigned int* __restrict__ h2, const int* __restrict__ csr,
                                                const int* __restrict__ offs, const int* __restrict__ indeg,
                                                const float* __restrict__ dinv, unsigned int* __restrict__ t2, int N){
  int i = blockIdx.x;
  int c2 = threadIdx.x;                         // 2 cols per thread
  float di = dinv[i];
  unsigned int hv = h2[(size_t)i*256 + c2];
  float ax = di * bf2f((unsigned short)(hv & 0xffffu));
  float ay = di * bf2f((unsigned short)(hv >> 16));
  int base = offs[i], cnt = indeg[i];
  for (int e = 0; e < cnt; e++){
    int r = csr[base + e];
    float w = dinv[r];
    unsigned int v = h2[(size_t)r*256 + c2];
    ax += w * bf2f((unsigned short)(v & 0xffffu));
    ay += w * bf2f((unsigned short)(v >> 16));
  }
  unsigned int o = ((unsigned int)f2bf(di * ay) << 16) | (unsigned int)f2bf(di * ax);
  t2[(size_t)i*256 + c2] = o;
}

// ---------------- z2 = t @ blockdiag(W2) + b2, bf16 in/out ----------------
__global__ __launch_bounds__(256) void k_mm2(const unsigned short* __restrict__ t, const float* __restrict__ W,
                                             const float* __restrict__ b, unsigned short* __restrict__ z2, int N){
  __shared__ float tl[16 * 512];                // 32 KB
  int n0 = blockIdx.x * 16;
  for (int q = threadIdx.x; q < 16 * 128; q += 256){   // ushort4 granules
    int nn = q >> 7, k4 = q & 127;
    int n = n0 + nn;
    float4 f;
    if (n < N){
      ushort4 u = ((const ushort4*)t)[(size_t)n*128 + k4];
      f.x = bf2f(u.x); f.y = bf2f(u.y); f.z = bf2f(u.z); f.w = bf2f(u.w);
    } else { f.x = f.y = f.z = f.w = 0.f; }
    ((float4*)tl)[nn*128 + k4] = f;
  }
  __syncthreads();
  int c0 = threadIdx.x, c1 = threadIdx.x + 256;
  int g0 = c0 >> 7, j0 = c0 & 127, g1 = c1 >> 7, j1 = c1 & 127;
  const float* Wa = W + (size_t)g0 * 16384 + j0;
  const float* Wb = W + (size_t)g1 * 16384 + j1;
  float acc0[16], acc1[16];
  #pragma unroll
  for (int nn = 0; nn < 16; nn++){ acc0[nn] = 0.f; acc1[nn] = 0.f; }
  for (int k = 0; k < 128; k += 4){
    float wa0 = Wa[(k+0)*128], wa1 = Wa[(k+1)*128], wa2 = Wa[(k+2)*128], wa3 = Wa[(k+3)*128];
    float wb0 = Wb[(k+0)*128], wb1 = Wb[(k+1)*128], wb2 = Wb[(k+2)*128], wb3 = Wb[(k+3)*128];
    #pragma unroll
    for (int nn = 0; nn < 16; nn++){
      float4 s0 = *(const float4*)&tl[nn*512 + g0*128 + k];
      float4 s1 = *(const float4*)&tl[nn*512 + g1*128 + k];
      acc0[nn] += s0.x*wa0 + s0.y*wa1 + s0.z*wa2 + s0.w*wa3;
      acc1[nn] += s1.x*wb0 + s1.y*wb1 + s1.z*wb2 + s1.w*wb3;
    }
  }
  float bb0 = b[c0], bb1 = b[c1];
  for (int nn = 0; nn < 16; nn++){
    int n = n0 + nn;
    if (n < N){
      z2[(size_t)n*512 + c0] = f2bf(acc0[nn] + bb0);
      z2[(size_t)n*512 + c1] = f2bf(acc1[nn] + bb1);
    }
  }
}

// ---------------- out = sum_g mix_g * prelu(BN(z2_g)) ----------------
__global__ void k_out(const unsigned short* __restrict__ z2, const float* __restrict__ scale,
                      const float* __restrict__ shift, const float* __restrict__ mixe,
                      const float* __restrict__ alpha_p, float* __restrict__ out, int N){
  float alpha = alpha_p[0];
  int idx = blockIdx.x * 256 + threadIdx.x;
  if (idx >= N * 128) return;
  int i = idx >> 7, j = idx & 127;
  float4 me = ((const float4*)mixe)[i];
  float mx = fmaxf(fmaxf(me.x, me.y), fmaxf(me.z, me.w));
  float e0 = __expf(me.x - mx), e1 = __expf(me.y - mx), e2 = __expf(me.z - mx), e3 = __expf(me.w - mx);
  float inv = 1.f / (e0 + e1 + e2 + e3);
  float r = 0.f;
  #pragma unroll
  for (int g = 0; g < 4; g++){
    int c = g * 128 + j;
    float v = bf2f(z2[(size_t)i*512 + c]) * scale[c] + shift[c];
    v = v > 0.f ? v : alpha * v;
    float m = (g == 0) ? e0 : (g == 1) ? e1 : (g == 2) ? e2 : e3;
    r += m * inv * v;
  }
  out[idx] = r;
}

extern "C" void kernel_launch(void* const* d_in, const int* in_sizes, int n_in,
                              void* d_out, int out_size, void* d_ws, size_t ws_size,
                              hipStream_t stream) {
  const float* x      = (const float*)d_in[0];
  const int*   ei     = (const int*)d_in[1];
  const float* W1     = (const float*)d_in[2];
  const float* b1     = (const float*)d_in[3];
  const float* W2     = (const float*)d_in[4];
  const float* b2     = (const float*)d_in[5];
  const float* gamma1 = (const float*)d_in[6];
  const float* beta1  = (const float*)d_in[7];
  const float* gamma2 = (const float*)d_in[8];
  const float* beta2  = (const float*)d_in[9];
  const float* alpha  = (const float*)d_in[10];
  const float* mixe   = (const float*)d_in[11];
  float* out = (float*)d_out;

  const int N = in_sizes[0] / 128;
  const int E = in_sizes[1] / 2;
  const int* rowv = ei;
  const int* colv = ei + E;

  char* w = (char*)d_ws;
  size_t off = 0;
  auto take = [&](size_t bytes) -> void* {
    void* p = w + off;
    off = (off + bytes + 255) & ~(size_t)255;
    return p;
  };
  int*   indeg  = (int*)take((size_t)N * 4);
  int*   cursor = (int*)take((size_t)N * 4);
  int*   offs   = (int*)take((size_t)N * 4);
  int*   bsum   = (int*)take(4096);
  float* dinv   = (float*)take((size_t)N * 4);
  float* sum1   = (float*)take(2048);
  float* sq1    = (float*)take(2048);
  float* sum2   = (float*)take(2048);
  float* sq2    = (float*)take(2048);
  float* scale1 = (float*)take(2048);
  float* shift1 = (float*)take(2048);
  float* scale2 = (float*)take(2048);
  float* shift2 = (float*)take(2048);
  int*   csr    = (int*)take((size_t)E * 4);
  float* sbuf   = (float*)take((size_t)N * 128 * 4);
  unsigned short* z  = (unsigned short*)take((size_t)N * 512 * 2);  // reused as t after k_h
  unsigned short* h  = (unsigned short*)take((size_t)N * 512 * 2);
  unsigned short* z2 = (unsigned short*)take((size_t)N * 512 * 2);

  hipMemsetAsync(indeg, 0, (size_t)N * 4, stream);
  hipMemsetAsync(sum1, 0, 4 * 2048, stream);   // sum1, sq1, sum2, sq2 contiguous

  int ebl = (E + 255) / 256;
  int nb  = (N + 255) / 256;

  k_deg<<<ebl, 256, 0, stream>>>(colv, indeg, N, E);
  k_blocksum<<<nb, 256, 0, stream>>>(indeg, bsum, N);
  k_scan_bsum<<<1, 64, 0, stream>>>(bsum, nb);
  k_scan_node<<<nb, 256, 0, stream>>>(indeg, bsum, offs, cursor, dinv, N);
  k_scatter<<<ebl, 256, 0, stream>>>(rowv, colv, cursor, csr, N, E);

  k_prop_x<<<N, 128, 0, stream>>>(x, csr, offs, indeg, dinv, sbuf, N);
  k_mm1<<<(N + 15) / 16, 256, 0, stream>>>(sbuf, W1, b1, z, N);
  k_stats<<<dim3(2, 256), 256, 0, stream>>>(z, sum1, sq1, N);
  k_bnfix<<<2, 256, 0, stream>>>(sum1, sq1, gamma1, beta1, scale1, shift1, N);
  k_h<<<2048, 256, 0, stream>>>(z, scale1, shift1, alpha, h, N * 128);
  k_prop_h<<<N, 256, 0, stream>>>((const unsigned int*)h, csr, offs, indeg, dinv, (unsigned int*)z, N);
  k_mm2<<<(N + 15) / 16, 256, 0, stream>>>(z, W2, b2, z2, N);
  k_stats<<<dim3(2, 256), 256, 0, stream>>>(z2, sum2, sq2, N);
  k_bnfix<<<2, 256, 0, stream>>>(sum2, sq2, gamma2, beta2, scale2, shift2, N);
  k_out<<<(N * 128 + 255) / 256, 256, 0, stream>>>(z2, scale2, shift2, mixe, alpha, out, N);
}

// Round 2
// 701.535 us; speedup vs baseline: 1.2895x; 1.2895x over previous
//
#include <hip/hip_runtime.h>
#include <stdint.h>

static constexpr float EPS = 1e-5f;

__device__ __forceinline__ float bf2f(unsigned short u){
  union { unsigned int i; float f; } v; v.i = ((unsigned int)u) << 16; return v.f;
}
__device__ __forceinline__ unsigned short f2bf(float f){
  union { float f; unsigned int i; } v; v.f = f;
  unsigned int x = v.i;
  x += 0x7fffu + ((x >> 16) & 1u);   // round-to-nearest-even
  return (unsigned short)(x >> 16);
}
__device__ __forceinline__ float lo16(unsigned int v){ return bf2f((unsigned short)(v & 0xffffu)); }
__device__ __forceinline__ float hi16(unsigned int v){ return bf2f((unsigned short)(v >> 16)); }
__device__ __forceinline__ unsigned int pack2(float a, float b){
  return ((unsigned int)f2bf(b) << 16) | (unsigned int)f2bf(a);
}

// ---------------- graph build: degree, prefix-scan, CSR scatter ----------------
__global__ void k_deg(const int* __restrict__ col, int* __restrict__ indeg, int N, int E){
  int e = blockIdx.x * 256 + threadIdx.x;
  if (e < E){
    unsigned c = (unsigned)col[e];
    if (c < (unsigned)N) atomicAdd(&indeg[c], 1);
  }
}

__global__ void k_blocksum(const int* __restrict__ indeg, int* __restrict__ bsum, int N){
  __shared__ int sm[256];
  int i = blockIdx.x * 256 + threadIdx.x;
  sm[threadIdx.x] = (i < N) ? indeg[i] : 0;
  __syncthreads();
  for (int d = 128; d > 0; d >>= 1){
    if (threadIdx.x < d) sm[threadIdx.x] += sm[threadIdx.x + d];
    __syncthreads();
  }
  if (threadIdx.x == 0) bsum[blockIdx.x] = sm[0];
}

__global__ void k_scan_bsum(int* bsum, int nb){
  if (threadIdx.x == 0 && blockIdx.x == 0){
    int acc = 0;
    for (int b = 0; b < nb; b++){ int v = bsum[b]; bsum[b] = acc; acc += v; }
  }
}

__global__ void k_scan_node(const int* __restrict__ indeg, const int* __restrict__ bsum,
                            int* __restrict__ offs, int* __restrict__ cursor,
                            float* __restrict__ dinv, int N){
  __shared__ int sm[256];
  int i = blockIdx.x * 256 + threadIdx.x;
  int v = (i < N) ? indeg[i] : 0;
  sm[threadIdx.x] = v;
  __syncthreads();
  for (int d = 1; d < 256; d <<= 1){
    int t = (threadIdx.x >= d) ? sm[threadIdx.x - d] : 0;
    __syncthreads();
    sm[threadIdx.x] += t;
    __syncthreads();
  }
  if (i < N){
    int o = bsum[blockIdx.x] + sm[threadIdx.x] - v;   // exclusive
    offs[i] = o; cursor[i] = o;
    dinv[i] = rsqrtf((float)(v + 1));                 // deg = indeg + self-loop
  }
}

__global__ void k_scatter(const int* __restrict__ row, const int* __restrict__ col,
                          int* __restrict__ cursor, int* __restrict__ csr, int N, int E){
  int e = blockIdx.x * 256 + threadIdx.x;
  if (e < E){
    unsigned c = (unsigned)col[e];
    if (c < (unsigned)N){
      int p = atomicAdd(&cursor[c], 1);
      unsigned r = (unsigned)row[e];
      csr[p] = (r < (unsigned)N) ? (int)r : 0;
    }
  }
}

// ---------------- xs = bf16(dinv_i * x_i)  (pre-scaled, bf16) ----------------
__global__ void k_castx(const float* __restrict__ x, const float* __restrict__ dinv,
                        unsigned short* __restrict__ xs, int total4){
  int idx = blockIdx.x * 256 + threadIdx.x;
  int stride = gridDim.x * 256;
  for (; idx < total4; idx += stride){
    int i = idx >> 5;                       // 32 float4-granules per row (128 cols)
    float di = dinv[i];
    float4 v = ((const float4*)x)[idx];
    ushort4 o;
    o.x = f2bf(di * v.x); o.y = f2bf(di * v.y);
    o.z = f2bf(di * v.z); o.w = f2bf(di * v.w);
    ((ushort4*)xs)[idx] = o;
  }
}

// ---------------- s = P x : gather pre-scaled bf16 rows, 4-wide unroll ----------------
__global__ __launch_bounds__(64) void k_prop_x(const unsigned int* __restrict__ xs2,
                                               const int* __restrict__ csr,
                                               const int* __restrict__ offs, const int* __restrict__ indeg,
                                               const float* __restrict__ dinv,
                                               unsigned int* __restrict__ s2, int N){
  int i = blockIdx.x;
  int c2 = threadIdx.x;                     // 64 u32 = 128 bf16 cols
  unsigned int sv = xs2[(size_t)i*64 + c2]; // self term (already dinv_i-scaled)
  float ax = lo16(sv), ay = hi16(sv);
  int e = offs[i], end = e + indeg[i];
  for (; e + 4 <= end; e += 4){
    int r0 = csr[e], r1 = csr[e+1], r2 = csr[e+2], r3 = csr[e+3];
    unsigned int v0 = xs2[(size_t)r0*64 + c2];
    unsigned int v1 = xs2[(size_t)r1*64 + c2];
    unsigned int v2 = xs2[(size_t)r2*64 + c2];
    unsigned int v3 = xs2[(size_t)r3*64 + c2];
    ax += lo16(v0) + lo16(v1) + lo16(v2) + lo16(v3);
    ay += hi16(v0) + hi16(v1) + hi16(v2) + hi16(v3);
  }
  for (; e < end; e++){
    unsigned int v = xs2[(size_t)csr[e]*64 + c2];
    ax += lo16(v); ay += hi16(v);
  }
  float di = dinv[i];
  s2[(size_t)i*64 + c2] = pack2(di * ax, di * ay);
}

// ---------------- z = s @ W1_all + b1  (bf16 in, bf16 out, fused col stats) ----------
__global__ __launch_bounds__(256) void k_mm1(const unsigned short* __restrict__ s, const float* __restrict__ W,
                                             const float* __restrict__ b, unsigned short* __restrict__ z,
                                             float* __restrict__ ssum, float* __restrict__ ssq, int N){
  __shared__ float sl[16 * 128];
  int n0 = blockIdx.x * 16;
  for (int q = threadIdx.x; q < 16 * 32; q += 256){   // ushort4 granules
    int nn = q >> 5, k4 = q & 31;
    int n = n0 + nn;
    float4 f;
    if (n < N){
      ushort4 u = ((const ushort4*)s)[(size_t)n*32 + k4];
      f.x = bf2f(u.x); f.y = bf2f(u.y); f.z = bf2f(u.z); f.w = bf2f(u.w);
    } else { f.x = f.y = f.z = f.w = 0.f; }
    ((float4*)sl)[nn*32 + k4] = f;
  }
  __syncthreads();
  int c0 = threadIdx.x, c1 = threadIdx.x + 256;
  const float* Wa = W + (size_t)(c0 >> 7) * 16384 + (c0 & 127);
  const float* Wb = W + (size_t)(c1 >> 7) * 16384 + (c1 & 127);
  float acc0[16], acc1[16];
  #pragma unroll
  for (int nn = 0; nn < 16; nn++){ acc0[nn] = 0.f; acc1[nn] = 0.f; }
  for (int k = 0; k < 128; k += 4){
    float wa0 = Wa[(k+0)*128], wa1 = Wa[(k+1)*128], wa2 = Wa[(k+2)*128], wa3 = Wa[(k+3)*128];
    float wb0 = Wb[(k+0)*128], wb1 = Wb[(k+1)*128], wb2 = Wb[(k+2)*128], wb3 = Wb[(k+3)*128];
    #pragma unroll
    for (int nn = 0; nn < 16; nn++){
      float4 sv = *(const float4*)&sl[nn*128 + k];
      acc0[nn] += sv.x*wa0 + sv.y*wa1 + sv.z*wa2 + sv.w*wa3;
      acc1[nn] += sv.x*wb0 + sv.y*wb1 + sv.z*wb2 + sv.w*wb3;
    }
  }
  float bb0 = b[c0], bb1 = b[c1];
  float ps0 = 0.f, pq0 = 0.f, ps1 = 0.f, pq1 = 0.f;
  for (int nn = 0; nn < 16; nn++){
    int n = n0 + nn;
    if (n < N){
      float v0 = acc0[nn] + bb0, v1 = acc1[nn] + bb1;
      ps0 += v0; pq0 += v0*v0; ps1 += v1; pq1 += v1*v1;
      z[(size_t)n*512 + c0] = f2bf(v0);
      z[(size_t)n*512 + c1] = f2bf(v1);
    }
  }
  atomicAdd(&ssum[c0], ps0); atomicAdd(&ssq[c0], pq0);
  atomicAdd(&ssum[c1], ps1); atomicAdd(&ssq[c1], pq1);
}

__global__ void k_bnfix(const float* __restrict__ ssum, const float* __restrict__ ssq,
                        const float* __restrict__ gamma, const float* __restrict__ beta,
                        float* __restrict__ scale, float* __restrict__ shift, int N){
  int c = blockIdx.x * 256 + threadIdx.x;
  if (c < 512){
    float mean = ssum[c] / (float)N;
    float var  = ssq[c] / (float)N - mean * mean;
    float rstd = rsqrtf(var + EPS);
    float sc = rstd * gamma[c];
    scale[c] = sc;
    shift[c] = beta[c] - mean * sc;
  }
}

// ---------------- h' = dinv_i * prelu(BN(z)), bf16 ----------------
__global__ void k_h(const unsigned short* __restrict__ z, const float* __restrict__ scale,
                    const float* __restrict__ shift, const float* __restrict__ alpha_p,
                    const float* __restrict__ dinv,
                    unsigned short* __restrict__ h, int total4){
  float alpha = alpha_p[0];
  int idx = blockIdx.x * 256 + threadIdx.x;
  int stride = gridDim.x * 256;
  for (; idx < total4; idx += stride){
    ushort4 u = ((const ushort4*)z)[idx];
    int c4 = idx & 127;                         // 128 ushort4-granules per 512-row
    int i  = idx >> 7;
    float di = dinv[i];
    float4 sc = ((const float4*)scale)[c4];
    float4 sh = ((const float4*)shift)[c4];
    float a0 = bf2f(u.x)*sc.x + sh.x; a0 = a0 > 0.f ? a0 : alpha*a0;
    float a1 = bf2f(u.y)*sc.y + sh.y; a1 = a1 > 0.f ? a1 : alpha*a1;
    float a2 = bf2f(u.z)*sc.z + sh.z; a2 = a2 > 0.f ? a2 : alpha*a2;
    float a3 = bf2f(u.w)*sc.w + sh.w; a3 = a3 > 0.f ? a3 : alpha*a3;
    ushort4 o; o.x = f2bf(di*a0); o.y = f2bf(di*a1); o.z = f2bf(di*a2); o.w = f2bf(di*a3);
    ((ushort4*)h)[idx] = o;
  }
}

// ---------------- t = P h : gather pre-scaled bf16 rows, 4-wide unroll ----------------
__global__ __launch_bounds__(256) void k_prop_h(const unsigned int* __restrict__ h2,
                                                const int* __restrict__ csr,
                                                const int* __restrict__ offs, const int* __restrict__ indeg,
                                                const float* __restrict__ dinv,
                                                unsigned int* __restrict__ t2, int N){
  int i = blockIdx.x;
  int c2 = threadIdx.x;                         // 256 u32 = 512 bf16 cols
  unsigned int sv = h2[(size_t)i*256 + c2];     // self (already dinv_i-scaled)
  float ax = lo16(sv), ay = hi16(sv);
  int e = offs[i], end = e + indeg[i];
  for (; e + 4 <= end; e += 4){
    int r0 = csr[e], r1 = csr[e+1], r2 = csr[e+2], r3 = csr[e+3];
    unsigned int v0 = h2[(size_t)r0*256 + c2];
    unsigned int v1 = h2[(size_t)r1*256 + c2];
    unsigned int v2 = h2[(size_t)r2*256 + c2];
    unsigned int v3 = h2[(size_t)r3*256 + c2];
    ax += lo16(v0) + lo16(v1) + lo16(v2) + lo16(v3);
    ay += hi16(v0) + hi16(v1) + hi16(v2) + hi16(v3);
  }
  for (; e < end; e++){
    unsigned int v = h2[(size_t)csr[e]*256 + c2];
    ax += lo16(v); ay += hi16(v);
  }
  float di = dinv[i];
  t2[(size_t)i*256 + c2] = pack2(di * ax, di * ay);
}

// ---------------- z2 = t @ blockdiag(W2) + b2, bf16 in/out, fused col stats --------
__global__ __launch_bounds__(256) void k_mm2(const unsigned short* __restrict__ t, const float* __restrict__ W,
                                             const float* __restrict__ b, unsigned short* __restrict__ z2,
                                             float* __restrict__ ssum, float* __restrict__ ssq, int N){
  __shared__ float tl[16 * 512];                // 32 KB
  int n0 = blockIdx.x * 16;
  for (int q = threadIdx.x; q < 16 * 128; q += 256){   // ushort4 granules
    int nn = q >> 7, k4 = q & 127;
    int n = n0 + nn;
    float4 f;
    if (n < N){
      ushort4 u = ((const ushort4*)t)[(size_t)n*128 + k4];
      f.x = bf2f(u.x); f.y = bf2f(u.y); f.z = bf2f(u.z); f.w = bf2f(u.w);
    } else { f.x = f.y = f.z = f.w = 0.f; }
    ((float4*)tl)[nn*128 + k4] = f;
  }
  __syncthreads();
  int c0 = threadIdx.x, c1 = threadIdx.x + 256;
  int g0 = c0 >> 7, j0 = c0 & 127, g1 = c1 >> 7, j1 = c1 & 127;
  const float* Wa = W + (size_t)g0 * 16384 + j0;
  const float* Wb = W + (size_t)g1 * 16384 + j1;
  float acc0[16], acc1[16];
  #pragma unroll
  for (int nn = 0; nn < 16; nn++){ acc0[nn] = 0.f; acc1[nn] = 0.f; }
  for (int k = 0; k < 128; k += 4){
    float wa0 = Wa[(k+0)*128], wa1 = Wa[(k+1)*128], wa2 = Wa[(k+2)*128], wa3 = Wa[(k+3)*128];
    float wb0 = Wb[(k+0)*128], wb1 = Wb[(k+1)*128], wb2 = Wb[(k+2)*128], wb3 = Wb[(k+3)*128];
    #pragma unroll
    for (int nn = 0; nn < 16; nn++){
      float4 s0 = *(const float4*)&tl[nn*512 + g0*128 + k];
      float4 s1 = *(const float4*)&tl[nn*512 + g1*128 + k];
      acc0[nn] += s0.x*wa0 + s0.y*wa1 + s0.z*wa2 + s0.w*wa3;
      acc1[nn] += s1.x*wb0 + s1.y*wb1 + s1.z*wb2 + s1.w*wb3;
    }
  }
  float bb0 = b[c0], bb1 = b[c1];
  float ps0 = 0.f, pq0 = 0.f, ps1 = 0.f, pq1 = 0.f;
  for (int nn = 0; nn < 16; nn++){
    int n = n0 + nn;
    if (n < N){
      float v0 = acc0[nn] + bb0, v1 = acc1[nn] + bb1;
      ps0 += v0; pq0 += v0*v0; ps1 += v1; pq1 += v1*v1;
      z2[(size_t)n*512 + c0] = f2bf(v0);
      z2[(size_t)n*512 + c1] = f2bf(v1);
    }
  }
  atomicAdd(&ssum[c0], ps0); atomicAdd(&ssq[c0], pq0);
  atomicAdd(&ssum[c1], ps1); atomicAdd(&ssq[c1], pq1);
}

// ---------------- out = sum_g mix_g * prelu(BN(z2_g)) ----------------
__global__ void k_out(const unsigned short* __restrict__ z2, const float* __restrict__ scale,
                      const float* __restrict__ shift, const float* __restrict__ mixe,
                      const float* __restrict__ alpha_p, float* __restrict__ out, int N){
  float alpha = alpha_p[0];
  int idx = blockIdx.x * 256 + threadIdx.x;
  if (idx >= N * 128) return;
  int i = idx >> 7, j = idx & 127;
  float4 me = ((const float4*)mixe)[i];
  float mx = fmaxf(fmaxf(me.x, me.y), fmaxf(me.z, me.w));
  float e0 = __expf(me.x - mx), e1 = __expf(me.y - mx), e2 = __expf(me.z - mx), e3 = __expf(me.w - mx);
  float inv = 1.f / (e0 + e1 + e2 + e3);
  float r = 0.f;
  #pragma unroll
  for (int g = 0; g < 4; g++){
    int c = g * 128 + j;
    float v = bf2f(z2[(size_t)i*512 + c]) * scale[c] + shift[c];
    v = v > 0.f ? v : alpha * v;
    float m = (g == 0) ? e0 : (g == 1) ? e1 : (g == 2) ? e2 : e3;
    r += m * inv * v;
  }
  out[idx] = r;
}

extern "C" void kernel_launch(void* const* d_in, const int* in_sizes, int n_in,
                              void* d_out, int out_size, void* d_ws, size_t ws_size,
                              hipStream_t stream) {
  const float* x      = (const float*)d_in[0];
  const int*   ei     = (const int*)d_in[1];
  const float* W1     = (const float*)d_in[2];
  const float* b1     = (const float*)d_in[3];
  const float* W2     = (const float*)d_in[4];
  const float* b2     = (const float*)d_in[5];
  const float* gamma1 = (const float*)d_in[6];
  const float* beta1  = (const float*)d_in[7];
  const float* gamma2 = (const float*)d_in[8];
  const float* beta2  = (const float*)d_in[9];
  const float* alpha  = (const float*)d_in[10];
  const float* mixe   = (const float*)d_in[11];
  float* out = (float*)d_out;

  const int N = in_sizes[0] / 128;
  const int E = in_sizes[1] / 2;
  const int* rowv = ei;
  const int* colv = ei + E;

  char* w = (char*)d_ws;
  size_t off = 0;
  auto take = [&](size_t bytes) -> void* {
    void* p = w + off;
    off = (off + bytes + 255) & ~(size_t)255;
    return p;
  };
  int*   indeg  = (int*)take((size_t)N * 4);
  int*   cursor = (int*)take((size_t)N * 4);
  int*   offs   = (int*)take((size_t)N * 4);
  int*   bsum   = (int*)take(4096);
  float* dinv   = (float*)take((size_t)N * 4);
  float* sum1   = (float*)take(2048);
  float* sq1    = (float*)take(2048);
  float* sum2   = (float*)take(2048);
  float* sq2    = (float*)take(2048);
  float* scale1 = (float*)take(2048);
  float* shift1 = (float*)take(2048);
  float* scale2 = (float*)take(2048);
  float* shift2 = (float*)take(2048);
  int*   csr    = (int*)take((size_t)E * 4);
  unsigned short* xs = (unsigned short*)take((size_t)N * 128 * 2);
  unsigned short* sb = (unsigned short*)take((size_t)N * 128 * 2);
  unsigned short* z  = (unsigned short*)take((size_t)N * 512 * 2);  // reused as t after k_h
  unsigned short* h  = (unsigned short*)take((size_t)N * 512 * 2);
  unsigned short* z2 = (unsigned short*)take((size_t)N * 512 * 2);

  hipMemsetAsync(indeg, 0, (size_t)N * 4, stream);
  hipMemsetAsync(sum1, 0, 4 * 2048, stream);   // sum1, sq1, sum2, sq2 contiguous

  int ebl = (E + 255) / 256;
  int nb  = (N + 255) / 256;

  k_deg<<<ebl, 256, 0, stream>>>(colv, indeg, N, E);
  k_blocksum<<<nb, 256, 0, stream>>>(indeg, bsum, N);
  k_scan_bsum<<<1, 64, 0, stream>>>(bsum, nb);
  k_scan_node<<<nb, 256, 0, stream>>>(indeg, bsum, offs, cursor, dinv, N);
  k_scatter<<<ebl, 256, 0, stream>>>(rowv, colv, cursor, csr, N, E);

  k_castx<<<512, 256, 0, stream>>>(x, dinv, xs, N * 32);
  k_prop_x<<<N, 64, 0, stream>>>((const unsigned int*)xs, csr, offs, indeg, dinv, (unsigned int*)sb, N);
  k_mm1<<<(N + 15) / 16, 256, 0, stream>>>(sb, W1, b1, z, sum1, sq1, N);
  k_bnfix<<<2, 256, 0, stream>>>(sum1, sq1, gamma1, beta1, scale1, shift1, N);
  k_h<<<2048, 256, 0, stream>>>(z, scale1, shift1, alpha, dinv, h, N * 128);
  k_prop_h<<<N, 256, 0, stream>>>((const unsigned int*)h, csr, offs, indeg, dinv, (unsigned int*)z, N);
  k_mm2<<<(N + 15) / 16, 256, 0, stream>>>(z, W2, b2, z2, sum2, sq2, N);
  k_bnfix<<<2, 256, 0, stream>>>(sum2, sq2, gamma2, beta2, scale2, shift2, N);
  k_out<<<(N * 128 + 255) / 256, 256, 0, stream>>>(z2, scale2, shift2, mixe, alpha, out, N);
}

// Round 3
// 624.132 us; speedup vs baseline: 1.4494x; 1.1240x over previous
//
#include <hip/hip_runtime.h>
#include <stdint.h>

static constexpr float EPS = 1e-5f;

typedef __attribute__((ext_vector_type(8))) short bfrag;
typedef __attribute__((ext_vector_type(4))) float ffrag;

__device__ __forceinline__ float bf2f(unsigned short u){
  union { unsigned int i; float f; } v; v.i = ((unsigned int)u) << 16; return v.f;
}
__device__ __forceinline__ unsigned short f2bf(float f){
  union { float f; unsigned int i; } v; v.f = f;
  unsigned int x = v.i;
  x += 0x7fffu + ((x >> 16) & 1u);   // round-to-nearest-even
  return (unsigned short)(x >> 16);
}
__device__ __forceinline__ float lo16(unsigned int v){ return bf2f((unsigned short)(v & 0xffffu)); }
__device__ __forceinline__ float hi16(unsigned int v){ return bf2f((unsigned short)(v >> 16)); }
__device__ __forceinline__ unsigned int pack2(float a, float b){
  return ((unsigned int)f2bf(b) << 16) | (unsigned int)f2bf(a);
}

// ---------------- graph build: degree, prefix-scan, CSR scatter ----------------
__global__ void k_deg(const int* __restrict__ col, int* __restrict__ indeg, int N, int E){
  int e = blockIdx.x * 256 + threadIdx.x;
  if (e < E){
    unsigned c = (unsigned)col[e];
    if (c < (unsigned)N) atomicAdd(&indeg[c], 1);
  }
}

__global__ void k_blocksum(const int* __restrict__ indeg, int* __restrict__ bsum, int N){
  __shared__ int sm[256];
  int i = blockIdx.x * 256 + threadIdx.x;
  sm[threadIdx.x] = (i < N) ? indeg[i] : 0;
  __syncthreads();
  for (int d = 128; d > 0; d >>= 1){
    if (threadIdx.x < d) sm[threadIdx.x] += sm[threadIdx.x + d];
    __syncthreads();
  }
  if (threadIdx.x == 0) bsum[blockIdx.x] = sm[0];
}

__global__ void k_scan_bsum(int* bsum, int nb){
  if (threadIdx.x == 0 && blockIdx.x == 0){
    int acc = 0;
    for (int b = 0; b < nb; b++){ int v = bsum[b]; bsum[b] = acc; acc += v; }
  }
}

__global__ void k_scan_node(const int* __restrict__ indeg, const int* __restrict__ bsum,
                            int* __restrict__ offs, int* __restrict__ cursor,
                            float* __restrict__ dinv, int N){
  __shared__ int sm[256];
  int i = blockIdx.x * 256 + threadIdx.x;
  int v = (i < N) ? indeg[i] : 0;
  sm[threadIdx.x] = v;
  __syncthreads();
  for (int d = 1; d < 256; d <<= 1){
    int t = (threadIdx.x >= d) ? sm[threadIdx.x - d] : 0;
    __syncthreads();
    sm[threadIdx.x] += t;
    __syncthreads();
  }
  if (i < N){
    int o = bsum[blockIdx.x] + sm[threadIdx.x] - v;   // exclusive
    offs[i] = o; cursor[i] = o;
    dinv[i] = rsqrtf((float)(v + 1));                 // deg = indeg + self-loop
  }
}

__global__ void k_scatter(const int* __restrict__ row, const int* __restrict__ col,
                          int* __restrict__ cursor, int* __restrict__ csr, int N, int E){
  int e = blockIdx.x * 256 + threadIdx.x;
  if (e < E){
    unsigned c = (unsigned)col[e];
    if (c < (unsigned)N){
      int p = atomicAdd(&cursor[c], 1);
      unsigned r = (unsigned)row[e];
      csr[p] = (r < (unsigned)N) ? (int)r : 0;
    }
  }
}

// ---------------- W transpose + bf16 cast: Wt[c][k] = W[c>>7][k][c&127] ----------------
__global__ void k_wcast(const float* __restrict__ W, unsigned short* __restrict__ Wt, int total){
  int idx = blockIdx.x * 256 + threadIdx.x;   // idx = c*128 + k
  if (idx < total){
    int c = idx >> 7, k = idx & 127;
    int g = c >> 7, j = c & 127;
    Wt[idx] = f2bf(W[(size_t)g*16384 + k*128 + j]);
  }
}

// ---------------- xs = bf16(dinv_i * x_i)  (pre-scaled, bf16) ----------------
__global__ void k_castx(const float* __restrict__ x, const float* __restrict__ dinv,
                        unsigned short* __restrict__ xs, int total4){
  int idx = blockIdx.x * 256 + threadIdx.x;
  int stride = gridDim.x * 256;
  for (; idx < total4; idx += stride){
    int i = idx >> 5;                       // 32 float4-granules per row (128 cols)
    float di = dinv[i];
    float4 v = ((const float4*)x)[idx];
    ushort4 o;
    o.x = f2bf(di * v.x); o.y = f2bf(di * v.y);
    o.z = f2bf(di * v.z); o.w = f2bf(di * v.w);
    ((ushort4*)xs)[idx] = o;
  }
}

// ---------------- s = P x : gather pre-scaled bf16 rows, 4-wide unroll ----------------
__global__ __launch_bounds__(64) void k_prop_x(const unsigned int* __restrict__ xs2,
                                               const int* __restrict__ csr,
                                               const int* __restrict__ offs, const int* __restrict__ indeg,
                                               const float* __restrict__ dinv,
                                               unsigned int* __restrict__ s2, int N){
  int i = blockIdx.x;
  int c2 = threadIdx.x;                     // 64 u32 = 128 bf16 cols
  unsigned int sv = xs2[(size_t)i*64 + c2]; // self term (already dinv_i-scaled)
  float ax = lo16(sv), ay = hi16(sv);
  int e = offs[i], end = e + indeg[i];
  for (; e + 4 <= end; e += 4){
    int r0 = csr[e], r1 = csr[e+1], r2 = csr[e+2], r3 = csr[e+3];
    unsigned int v0 = xs2[(size_t)r0*64 + c2];
    unsigned int v1 = xs2[(size_t)r1*64 + c2];
    unsigned int v2 = xs2[(size_t)r2*64 + c2];
    unsigned int v3 = xs2[(size_t)r3*64 + c2];
    ax += lo16(v0) + lo16(v1) + lo16(v2) + lo16(v3);
    ay += hi16(v0) + hi16(v1) + hi16(v2) + hi16(v3);
  }
  for (; e < end; e++){
    unsigned int v = xs2[(size_t)csr[e]*64 + c2];
    ax += lo16(v); ay += hi16(v);
  }
  float di = dinv[i];
  s2[(size_t)i*64 + c2] = pack2(di * ax, di * ay);
}

// ---------------- unified MFMA GEMM: out[n][c] = in[n][kofs(c)+k] * Wt[c][k] + bias[c] ----
// Block: 16 nodes x 512 cols, 4 waves; wave w owns cols [w*128, w*128+128).
// kmul=0   : shared K (mm1, in_stride=128)
// kmul=128 : block-diagonal, wave w reads K-slice w*128 (mm2, in_stride=512)
__global__ __launch_bounds__(256) void k_mm_mfma(const unsigned short* __restrict__ in,
                                                 const unsigned short* __restrict__ Wt,
                                                 const float* __restrict__ bias,
                                                 unsigned short* __restrict__ out,
                                                 int N, int in_stride, int kmul){
  int wave = threadIdx.x >> 6;
  int lane = threadIdx.x & 63;
  int l16 = lane & 15, quad = lane >> 4;
  int node = blockIdx.x * 16 + l16;          // N % 16 == 0 in this problem
  int nc = node < N ? node : N - 1;
  int colbase0 = wave * 128;
  int kofs = kmul * wave;

  const unsigned short* inrow = in + (size_t)nc * in_stride + kofs + quad * 8;
  bfrag b0 = *(const bfrag*)(inrow);
  bfrag b1 = *(const bfrag*)(inrow + 32);
  bfrag b2 = *(const bfrag*)(inrow + 64);
  bfrag b3 = *(const bfrag*)(inrow + 96);

  #pragma unroll
  for (int ct = 0; ct < 8; ct++){
    int colbase = colbase0 + ct * 16;
    const unsigned short* wrow = Wt + (size_t)(colbase + l16) * 128 + quad * 8;
    bfrag a0 = *(const bfrag*)(wrow);
    bfrag a1 = *(const bfrag*)(wrow + 32);
    bfrag a2 = *(const bfrag*)(wrow + 64);
    bfrag a3 = *(const bfrag*)(wrow + 96);
    ffrag acc = {0.f, 0.f, 0.f, 0.f};
    acc = __builtin_amdgcn_mfma_f32_16x16x32_bf16(a0, b0, acc, 0, 0, 0);
    acc = __builtin_amdgcn_mfma_f32_16x16x32_bf16(a1, b1, acc, 0, 0, 0);
    acc = __builtin_amdgcn_mfma_f32_16x16x32_bf16(a2, b2, acc, 0, 0, 0);
    acc = __builtin_amdgcn_mfma_f32_16x16x32_bf16(a3, b3, acc, 0, 0, 0);
    // lane's 4 results = cols colbase+quad*4+{0..3} of `node`
    float4 bb = *(const float4*)(bias + colbase + quad * 4);
    uint2 o;
    o.x = pack2(acc[0] + bb.x, acc[1] + bb.y);
    o.y = pack2(acc[2] + bb.z, acc[3] + bb.w);
    if (node < N)
      *(uint2*)(out + (size_t)node * 512 + colbase + quad * 4) = o;
  }
}

// ---------------- per-column stats over bf16 (N x 512), register accumulation -------
__global__ __launch_bounds__(256) void k_stats(const unsigned int* __restrict__ z2,
                                               float* __restrict__ ssum, float* __restrict__ ssq, int N){
  int t = threadIdx.x;                       // owns cols 2t, 2t+1
  int rpb = (N + gridDim.x - 1) / gridDim.x;
  int r0 = blockIdx.x * rpb;
  int r1 = min(N, r0 + rpb);
  float s0 = 0.f, q0 = 0.f, s1 = 0.f, q1 = 0.f;
  for (int r = r0; r < r1; r++){
    unsigned int v = z2[(size_t)r * 256 + t];
    float a = lo16(v), b = hi16(v);
    s0 += a; q0 += a * a; s1 += b; q1 += b * b;
  }
  atomicAdd(&ssum[2 * t], s0);     atomicAdd(&ssq[2 * t], q0);
  atomicAdd(&ssum[2 * t + 1], s1); atomicAdd(&ssq[2 * t + 1], q1);
}

__global__ void k_bnfix(const float* __restrict__ ssum, const float* __restrict__ ssq,
                        const float* __restrict__ gamma, const float* __restrict__ beta,
                        float* __restrict__ scale, float* __restrict__ shift, int N){
  int c = blockIdx.x * 256 + threadIdx.x;
  if (c < 512){
    float mean = ssum[c] / (float)N;
    float var  = ssq[c] / (float)N - mean * mean;
    float rstd = rsqrtf(var + EPS);
    float sc = rstd * gamma[c];
    scale[c] = sc;
    shift[c] = beta[c] - mean * sc;
  }
}

// ---------------- h' = dinv_i * prelu(BN(z)), bf16 ----------------
__global__ void k_h(const unsigned short* __restrict__ z, const float* __restrict__ scale,
                    const float* __restrict__ shift, const float* __restrict__ alpha_p,
                    const float* __restrict__ dinv,
                    unsigned short* __restrict__ h, int total4){
  float alpha = alpha_p[0];
  int idx = blockIdx.x * 256 + threadIdx.x;
  int stride = gridDim.x * 256;
  for (; idx < total4; idx += stride){
    ushort4 u = ((const ushort4*)z)[idx];
    int c4 = idx & 127;                         // 128 ushort4-granules per 512-row
    int i  = idx >> 7;
    float di = dinv[i];
    float4 sc = ((const float4*)scale)[c4];
    float4 sh = ((const float4*)shift)[c4];
    float a0 = bf2f(u.x)*sc.x + sh.x; a0 = a0 > 0.f ? a0 : alpha*a0;
    float a1 = bf2f(u.y)*sc.y + sh.y; a1 = a1 > 0.f ? a1 : alpha*a1;
    float a2 = bf2f(u.z)*sc.z + sh.z; a2 = a2 > 0.f ? a2 : alpha*a2;
    float a3 = bf2f(u.w)*sc.w + sh.w; a3 = a3 > 0.f ? a3 : alpha*a3;
    ushort4 o; o.x = f2bf(di*a0); o.y = f2bf(di*a1); o.z = f2bf(di*a2); o.w = f2bf(di*a3);
    ((ushort4*)h)[idx] = o;
  }
}

// ---------------- t = P h : gather pre-scaled bf16 rows, 4-wide unroll ----------------
__global__ __launch_bounds__(256) void k_prop_h(const unsigned int* __restrict__ h2,
                                                const int* __restrict__ csr,
                                                const int* __restrict__ offs, const int* __restrict__ indeg,
                                                const float* __restrict__ dinv,
                                                unsigned int* __restrict__ t2, int N){
  int i = blockIdx.x;
  int c2 = threadIdx.x;                         // 256 u32 = 512 bf16 cols
  unsigned int sv = h2[(size_t)i*256 + c2];     // self (already dinv_i-scaled)
  float ax = lo16(sv), ay = hi16(sv);
  int e = offs[i], end = e + indeg[i];
  for (; e + 4 <= end; e += 4){
    int r0 = csr[e], r1 = csr[e+1], r2 = csr[e+2], r3 = csr[e+3];
    unsigned int v0 = h2[(size_t)r0*256 + c2];
    unsigned int v1 = h2[(size_t)r1*256 + c2];
    unsigned int v2 = h2[(size_t)r2*256 + c2];
    unsigned int v3 = h2[(size_t)r3*256 + c2];
    ax += lo16(v0) + lo16(v1) + lo16(v2) + lo16(v3);
    ay += hi16(v0) + hi16(v1) + hi16(v2) + hi16(v3);
  }
  for (; e < end; e++){
    unsigned int v = h2[(size_t)csr[e]*256 + c2];
    ax += lo16(v); ay += hi16(v);
  }
  float di = dinv[i];
  t2[(size_t)i*256 + c2] = pack2(di * ax, di * ay);
}

// ---------------- out = sum_g mix_g * prelu(BN(z2_g)) ----------------
__global__ void k_out(const unsigned short* __restrict__ z2, const float* __restrict__ scale,
                      const float* __restrict__ shift, const float* __restrict__ mixe,
                      const float* __restrict__ alpha_p, float* __restrict__ out, int N){
  float alpha = alpha_p[0];
  int idx = blockIdx.x * 256 + threadIdx.x;
  if (idx >= N * 128) return;
  int i = idx >> 7, j = idx & 127;
  float4 me = ((const float4*)mixe)[i];
  float mx = fmaxf(fmaxf(me.x, me.y), fmaxf(me.z, me.w));
  float e0 = __expf(me.x - mx), e1 = __expf(me.y - mx), e2 = __expf(me.z - mx), e3 = __expf(me.w - mx);
  float inv = 1.f / (e0 + e1 + e2 + e3);
  float r = 0.f;
  #pragma unroll
  for (int g = 0; g < 4; g++){
    int c = g * 128 + j;
    float v = bf2f(z2[(size_t)i*512 + c]) * scale[c] + shift[c];
    v = v > 0.f ? v : alpha * v;
    float m = (g == 0) ? e0 : (g == 1) ? e1 : (g == 2) ? e2 : e3;
    r += m * inv * v;
  }
  out[idx] = r;
}

extern "C" void kernel_launch(void* const* d_in, const int* in_sizes, int n_in,
                              void* d_out, int out_size, void* d_ws, size_t ws_size,
                              hipStream_t stream) {
  const float* x      = (const float*)d_in[0];
  const int*   ei     = (const int*)d_in[1];
  const float* W1     = (const float*)d_in[2];
  const float* b1     = (const float*)d_in[3];
  const float* W2     = (const float*)d_in[4];
  const float* b2     = (const float*)d_in[5];
  const float* gamma1 = (const float*)d_in[6];
  const float* beta1  = (const float*)d_in[7];
  const float* gamma2 = (const float*)d_in[8];
  const float* beta2  = (const float*)d_in[9];
  const float* alpha  = (const float*)d_in[10];
  const float* mixe   = (const float*)d_in[11];
  float* out = (float*)d_out;

  const int N = in_sizes[0] / 128;
  const int E = in_sizes[1] / 2;
  const int* rowv = ei;
  const int* colv = ei + E;

  char* w = (char*)d_ws;
  size_t off = 0;
  auto take = [&](size_t bytes) -> void* {
    void* p = w + off;
    off = (off + bytes + 255) & ~(size_t)255;
    return p;
  };
  int*   indeg  = (int*)take((size_t)N * 4);
  int*   cursor = (int*)take((size_t)N * 4);
  int*   offs   = (int*)take((size_t)N * 4);
  int*   bsum   = (int*)take(4096);
  float* dinv   = (float*)take((size_t)N * 4);
  float* sum1   = (float*)take(2048);
  float* sq1    = (float*)take(2048);
  float* sum2   = (float*)take(2048);
  float* sq2    = (float*)take(2048);
  float* scale1 = (float*)take(2048);
  float* shift1 = (float*)take(2048);
  float* scale2 = (float*)take(2048);
  float* shift2 = (float*)take(2048);
  int*   csr    = (int*)take((size_t)E * 4);
  unsigned short* Wt1 = (unsigned short*)take(512 * 128 * 2);
  unsigned short* Wt2 = (unsigned short*)take(512 * 128 * 2);
  unsigned short* xs = (unsigned short*)take((size_t)N * 128 * 2);
  unsigned short* sb = (unsigned short*)take((size_t)N * 128 * 2);
  unsigned short* z  = (unsigned short*)take((size_t)N * 512 * 2);  // reused as t after k_h
  unsigned short* h  = (unsigned short*)take((size_t)N * 512 * 2);
  unsigned short* z2 = (unsigned short*)take((size_t)N * 512 * 2);

  hipMemsetAsync(indeg, 0, (size_t)N * 4, stream);
  hipMemsetAsync(sum1, 0, 4 * 2048, stream);   // sum1, sq1, sum2, sq2 contiguous

  int ebl = (E + 255) / 256;
  int nb  = (N + 255) / 256;

  k_deg<<<ebl, 256, 0, stream>>>(colv, indeg, N, E);
  k_blocksum<<<nb, 256, 0, stream>>>(indeg, bsum, N);
  k_scan_bsum<<<1, 64, 0, stream>>>(bsum, nb);
  k_scan_node<<<nb, 256, 0, stream>>>(indeg, bsum, offs, cursor, dinv, N);
  k_scatter<<<ebl, 256, 0, stream>>>(rowv, colv, cursor, csr, N, E);

  k_wcast<<<256, 256, 0, stream>>>(W1, Wt1, 512 * 128);
  k_wcast<<<256, 256, 0, stream>>>(W2, Wt2, 512 * 128);

  k_castx<<<512, 256, 0, stream>>>(x, dinv, xs, N * 32);
  k_prop_x<<<N, 64, 0, stream>>>((const unsigned int*)xs, csr, offs, indeg, dinv, (unsigned int*)sb, N);

  int mmb = (N + 15) / 16;
  k_mm_mfma<<<mmb, 256, 0, stream>>>(sb, Wt1, b1, z, N, 128, 0);
  k_stats<<<512, 256, 0, stream>>>((const unsigned int*)z, sum1, sq1, N);
  k_bnfix<<<2, 256, 0, stream>>>(sum1, sq1, gamma1, beta1, scale1, shift1, N);
  k_h<<<2048, 256, 0, stream>>>(z, scale1, shift1, alpha, dinv, h, N * 128);
  k_prop_h<<<N, 256, 0, stream>>>((const unsigned int*)h, csr, offs, indeg, dinv, (unsigned int*)z, N);
  k_mm_mfma<<<mmb, 256, 0, stream>>>(z, Wt2, b2, z2, N, 512, 128);
  k_stats<<<512, 256, 0, stream>>>((const unsigned int*)z2, sum2, sq2, N);
  k_bnfix<<<2, 256, 0, stream>>>(sum2, sq2, gamma2, beta2, scale2, shift2, N);
  k_out<<<(N * 128 + 255) / 256, 256, 0, stream>>>(z2, scale2, shift2, mixe, alpha, out, N);
}

// Round 4
// 600.914 us; speedup vs baseline: 1.5054x; 1.0386x over previous
//
#include <hip/hip_runtime.h>
#include <stdint.h>

static constexpr float EPS = 1e-5f;

typedef __attribute__((ext_vector_type(8))) short bfrag;
typedef __attribute__((ext_vector_type(4))) float ffrag;

__device__ __forceinline__ float bf2f(unsigned short u){
  union { unsigned int i; float f; } v; v.i = ((unsigned int)u) << 16; return v.f;
}
__device__ __forceinline__ unsigned short f2bf(float f){
  union { float f; unsigned int i; } v; v.f = f;
  unsigned int x = v.i;
  x += 0x7fffu + ((x >> 16) & 1u);   // round-to-nearest-even
  return (unsigned short)(x >> 16);
}
__device__ __forceinline__ float lo16(unsigned int v){ return bf2f((unsigned short)(v & 0xffffu)); }
__device__ __forceinline__ float hi16(unsigned int v){ return bf2f((unsigned short)(v >> 16)); }
__device__ __forceinline__ unsigned int pack2(float a, float b){
  return ((unsigned int)f2bf(b) << 16) | (unsigned int)f2bf(a);
}

// ---------------- graph build ----------------
__global__ void k_deg(const int* __restrict__ col, int* __restrict__ indeg, int N, int E){
  int e = blockIdx.x * 256 + threadIdx.x;
  if (e < E){
    unsigned c = (unsigned)col[e];
    if (c < (unsigned)N) atomicAdd(&indeg[c], 1);
  }
}

__global__ void k_blocksum(const int* __restrict__ indeg, int* __restrict__ bsum, int N){
  __shared__ int sm[256];
  int i = blockIdx.x * 256 + threadIdx.x;
  sm[threadIdx.x] = (i < N) ? indeg[i] : 0;
  __syncthreads();
  for (int d = 128; d > 0; d >>= 1){
    if (threadIdx.x < d) sm[threadIdx.x] += sm[threadIdx.x + d];
    __syncthreads();
  }
  if (threadIdx.x == 0) bsum[blockIdx.x] = sm[0];
}

// parallel exclusive scan of block sums (nb <= 1024)
__global__ __launch_bounds__(1024) void k_scan_bsum(int* bsum, int nb){
  __shared__ int sm[1024];
  int t = threadIdx.x;
  int v = (t < nb) ? bsum[t] : 0;
  sm[t] = v;
  __syncthreads();
  for (int d = 1; d < 1024; d <<= 1){
    int u = (t >= d) ? sm[t - d] : 0;
    __syncthreads();
    sm[t] += u;
    __syncthreads();
  }
  if (t < nb) bsum[t] = sm[t] - v;   // exclusive
}

__global__ void k_scan_node(const int* __restrict__ indeg, const int* __restrict__ bsum,
                            int* __restrict__ offs, int* __restrict__ cursor,
                            float* __restrict__ dinv, int N){
  __shared__ int sm[256];
  int i = blockIdx.x * 256 + threadIdx.x;
  int v = (i < N) ? indeg[i] : 0;
  sm[threadIdx.x] = v;
  __syncthreads();
  for (int d = 1; d < 256; d <<= 1){
    int t = (threadIdx.x >= d) ? sm[threadIdx.x - d] : 0;
    __syncthreads();
    sm[threadIdx.x] += t;
    __syncthreads();
  }
  if (i < N){
    int o = bsum[blockIdx.x] + sm[threadIdx.x] - v;   // exclusive
    offs[i] = o; cursor[i] = o;
    dinv[i] = rsqrtf((float)(v + 1));                 // deg = indeg + self-loop
  }
}

__global__ void k_scatter(const int* __restrict__ row, const int* __restrict__ col,
                          int* __restrict__ cursor, int* __restrict__ csr, int N, int E){
  int e = blockIdx.x * 256 + threadIdx.x;
  if (e < E){
    unsigned c = (unsigned)col[e];
    if (c < (unsigned)N){
      int p = atomicAdd(&cursor[c], 1);
      unsigned r = (unsigned)row[e];
      csr[p] = (r < (unsigned)N) ? (int)r : 0;
    }
  }
}

// ---------------- W transpose + bf16 cast (both weights, one launch) ----------------
__global__ void k_wcast(const float* __restrict__ W1, const float* __restrict__ W2,
                        unsigned short* __restrict__ Wt1, unsigned short* __restrict__ Wt2){
  int idx = blockIdx.x * 256 + threadIdx.x;   // [0, 131072)
  const float* W = W1; unsigned short* Wt = Wt1;
  if (idx >= 65536){ idx -= 65536; W = W2; Wt = Wt2; }
  int c = idx >> 7, k = idx & 127;
  int g = c >> 7, j = c & 127;
  Wt[(size_t)c * 128 + k] = f2bf(W[(size_t)g*16384 + k*128 + j]);
}

// ---------------- xs = bf16(dinv_i * x_i) ----------------
__global__ void k_castx(const float* __restrict__ x, const float* __restrict__ dinv,
                        unsigned short* __restrict__ xs, int total4){
  int idx = blockIdx.x * 256 + threadIdx.x;
  int stride = gridDim.x * 256;
  for (; idx < total4; idx += stride){
    int i = idx >> 5;
    float di = dinv[i];
    float4 v = ((const float4*)x)[idx];
    ushort4 o;
    o.x = f2bf(di * v.x); o.y = f2bf(di * v.y);
    o.z = f2bf(di * v.z); o.w = f2bf(di * v.w);
    ((ushort4*)xs)[idx] = o;
  }
}

// ---------------- s = P x : 4 nodes/block, 8-wide unroll ----------------
__global__ __launch_bounds__(256) void k_prop_x(const unsigned int* __restrict__ xs2,
                                               const int* __restrict__ csr,
                                               const int* __restrict__ offs, const int* __restrict__ indeg,
                                               const float* __restrict__ dinv,
                                               unsigned int* __restrict__ s2, int N){
  int i = blockIdx.x * 4 + (threadIdx.x >> 6);
  if (i >= N) return;
  int c2 = threadIdx.x & 63;
  unsigned int sv = xs2[(size_t)i*64 + c2];
  float ax = lo16(sv), ay = hi16(sv);
  int e = offs[i], end = e + indeg[i];
  for (; e + 8 <= end; e += 8){
    int r0 = csr[e], r1 = csr[e+1], r2 = csr[e+2], r3 = csr[e+3];
    int r4 = csr[e+4], r5 = csr[e+5], r6 = csr[e+6], r7 = csr[e+7];
    unsigned int v0 = xs2[(size_t)r0*64 + c2], v1 = xs2[(size_t)r1*64 + c2];
    unsigned int v2 = xs2[(size_t)r2*64 + c2], v3 = xs2[(size_t)r3*64 + c2];
    unsigned int v4 = xs2[(size_t)r4*64 + c2], v5 = xs2[(size_t)r5*64 + c2];
    unsigned int v6 = xs2[(size_t)r6*64 + c2], v7 = xs2[(size_t)r7*64 + c2];
    ax += lo16(v0)+lo16(v1)+lo16(v2)+lo16(v3)+lo16(v4)+lo16(v5)+lo16(v6)+lo16(v7);
    ay += hi16(v0)+hi16(v1)+hi16(v2)+hi16(v3)+hi16(v4)+hi16(v5)+hi16(v6)+hi16(v7);
  }
  for (; e < end; e++){
    unsigned int v = xs2[(size_t)csr[e]*64 + c2];
    ax += lo16(v); ay += hi16(v);
  }
  float di = dinv[i];
  s2[(size_t)i*64 + c2] = pack2(di * ax, di * ay);
}

// ---------------- Gram + column sums over a 128-col slice (MFMA) ----------------
// grid (NB, ngroups). in rows stride rstride, cols [gy*coff128, +128).
// G_out += slice^T slice (128x128), msum += column sums.
__global__ __launch_bounds__(256) void k_gram(const unsigned short* __restrict__ in,
                                              int rstride, int coff128,
                                              float* __restrict__ Gbase, float* __restrict__ msumbase,
                                              int N){
  int gy = blockIdx.y;
  const unsigned short* src = in + gy * coff128;
  float* G = Gbase + (size_t)gy * 16384;
  float* msum = msumbase + gy * 128;

  __shared__ unsigned short st[128 * 40];   // [col][node], row=40 u16 (80B, 16B-aligned)
  __shared__ float colsum[128];

  int t = threadIdx.x;
  int wv = t >> 6, lane = t & 63, l16 = lane & 15, quad = lane >> 4;
  if (t < 128) colsum[t] = 0.f;

  // staging mapping: n = t&31, cb = t>>5 (8 groups of 16 cols)
  int sn = t & 31, scb = t >> 5;

  ffrag acc[2][8];
  #pragma unroll
  for (int a = 0; a < 2; a++)
    #pragma unroll
    for (int b = 0; b < 8; b++) acc[a][b] = (ffrag){0.f,0.f,0.f,0.f};

  float cs[16];
  #pragma unroll
  for (int j = 0; j < 16; j++) cs[j] = 0.f;

  for (int c0 = blockIdx.x * 32; c0 < N; c0 += gridDim.x * 32){
    __syncthreads();
    // load 32 nodes x 128 cols, transpose into st
    int n = c0 + sn;
    ushort4 u0, u1, u2, u3;
    if (n < N){
      const ushort4* p = (const ushort4*)(src + (size_t)n * rstride + scb * 16);
      u0 = p[0]; u1 = p[1]; u2 = p[2]; u3 = p[3];
    } else {
      u0 = u1 = u2 = u3 = (ushort4){0,0,0,0};
    }
    unsigned short vals[16] = {u0.x,u0.y,u0.z,u0.w, u1.x,u1.y,u1.z,u1.w,
                               u2.x,u2.y,u2.z,u2.w, u3.x,u3.y,u3.z,u3.w};
    #pragma unroll
    for (int j = 0; j < 16; j++){
      st[(scb * 16 + j) * 40 + sn] = vals[j];
      cs[j] += bf2f(vals[j]);
    }
    __syncthreads();
    // MFMA: wave wv owns G rows [wv*32, wv*32+32)
    #pragma unroll
    for (int ta = 0; ta < 2; ta++){
      int ra = wv * 2 + ta;
      bfrag af = *(const bfrag*)&st[(ra * 16 + l16) * 40 + quad * 8];
      #pragma unroll
      for (int tb = 0; tb < 8; tb++){
        bfrag bf = *(const bfrag*)&st[(tb * 16 + l16) * 40 + quad * 8];
        acc[ta][tb] = __builtin_amdgcn_mfma_f32_16x16x32_bf16(af, bf, acc[ta][tb], 0, 0, 0);
      }
    }
  }
  // column sums: LDS reduce then global atomics
  #pragma unroll
  for (int j = 0; j < 16; j++) atomicAdd(&colsum[scb * 16 + j], cs[j]);
  __syncthreads();
  if (t < 128) atomicAdd(&msum[t], colsum[t]);
  // Gram: atomics to global
  #pragma unroll
  for (int ta = 0; ta < 2; ta++){
    #pragma unroll
    for (int tb = 0; tb < 8; tb++){
      int row0 = wv * 32 + ta * 16 + quad * 4;
      int colg = tb * 16 + l16;
      #pragma unroll
      for (int r = 0; r < 4; r++)
        atomicAdd(&G[(size_t)(row0 + r) * 128 + colg], acc[ta][tb][r]);
    }
  }
}

// ---------------- analytic BN coefficients from Gram ----------------
// per column c in [0,512): g=c>>7, j=c&127; w_c = W[g][:,j]
// mean0 = (msum/N)·w ; var = (w^T G w)/N - mean0^2
// scale = gamma*rsqrt(var+eps); shiftF = beta - mean0*scale  (bias b cancels)
__global__ __launch_bounds__(64) void k_bnfit(const float* __restrict__ W,
                                              const float* __restrict__ gamma, const float* __restrict__ beta,
                                              const float* __restrict__ Gbase, int gmul,
                                              const float* __restrict__ msumbase, int mmul,
                                              float* __restrict__ scale, float* __restrict__ shiftF,
                                              float invN){
  int c = blockIdx.x;
  int g = c >> 7, j = c & 127;
  const float* Wc = W + (size_t)g * 16384 + j;  // stride 128
  const float* G  = Gbase + (size_t)g * gmul;
  const float* mv = msumbase + g * mmul;
  __shared__ float wl[128];
  __shared__ float ml[128];
  int t = threadIdx.x;
  for (int k = t; k < 128; k += 64){ wl[k] = Wc[(size_t)k * 128]; ml[k] = mv[k] * invN; }
  __syncthreads();
  float quad = 0.f, dm = 0.f;
  #pragma unroll
  for (int kk = 0; kk < 2; kk++){
    int k = t + kk * 64;
    float wk = wl[k];
    dm += ml[k] * wk;
    const float* Gr = G + (size_t)k * 128;
    float p = 0.f;
    for (int jj = 0; jj < 128; jj += 4){
      float4 gg = *(const float4*)(Gr + jj);
      float4 ww = *(const float4*)(wl + jj);
      p += gg.x*ww.x + gg.y*ww.y + gg.z*ww.z + gg.w*ww.w;
    }
    quad += wk * p;
  }
  for (int o = 32; o > 0; o >>= 1){
    quad += __shfl_down(quad, o);
    dm   += __shfl_down(dm, o);
  }
  if (t == 0){
    float var = quad * invN - dm * dm;
    float sc = gamma[c] * rsqrtf(var + EPS);
    scale[c] = sc;
    shiftF[c] = beta[c] - dm * sc;
  }
}

// ---------------- mm1 fused: h = dinv * prelu(BN(s @ W1 + b1)) ----------------
__global__ __launch_bounds__(256) void k_mm1f(const unsigned short* __restrict__ in,
                                              const unsigned short* __restrict__ Wt,
                                              const float* __restrict__ scale, const float* __restrict__ shiftF,
                                              const float* __restrict__ alpha_p, const float* __restrict__ dinv,
                                              unsigned short* __restrict__ h, int N){
  float alpha = alpha_p[0];
  int wave = threadIdx.x >> 6, lane = threadIdx.x & 63;
  int l16 = lane & 15, quad = lane >> 4;
  int node = blockIdx.x * 16 + l16;
  int nc = node < N ? node : N - 1;
  int colbase0 = wave * 128;
  float di = dinv[nc];

  const unsigned short* inrow = in + (size_t)nc * 128 + quad * 8;
  bfrag b0 = *(const bfrag*)(inrow);
  bfrag b1 = *(const bfrag*)(inrow + 32);
  bfrag b2 = *(const bfrag*)(inrow + 64);
  bfrag b3 = *(const bfrag*)(inrow + 96);

  #pragma unroll
  for (int ct = 0; ct < 8; ct++){
    int colbase = colbase0 + ct * 16;
    const unsigned short* wrow = Wt + (size_t)(colbase + l16) * 128 + quad * 8;
    bfrag a0 = *(const bfrag*)(wrow);
    bfrag a1 = *(const bfrag*)(wrow + 32);
    bfrag a2 = *(const bfrag*)(wrow + 64);
    bfrag a3 = *(const bfrag*)(wrow + 96);
    ffrag acc = {0.f, 0.f, 0.f, 0.f};
    acc = __builtin_amdgcn_mfma_f32_16x16x32_bf16(a0, b0, acc, 0, 0, 0);
    acc = __builtin_amdgcn_mfma_f32_16x16x32_bf16(a1, b1, acc, 0, 0, 0);
    acc = __builtin_amdgcn_mfma_f32_16x16x32_bf16(a2, b2, acc, 0, 0, 0);
    acc = __builtin_amdgcn_mfma_f32_16x16x32_bf16(a3, b3, acc, 0, 0, 0);
    int cb = colbase + quad * 4;
    float4 sc = *(const float4*)(scale + cb);
    float4 sh = *(const float4*)(shiftF + cb);
    float v0 = acc[0]*sc.x + sh.x; v0 = v0 > 0.f ? v0 : alpha*v0;
    float v1 = acc[1]*sc.y + sh.y; v1 = v1 > 0.f ? v1 : alpha*v1;
    float v2 = acc[2]*sc.z + sh.z; v2 = v2 > 0.f ? v2 : alpha*v2;
    float v3 = acc[3]*sc.w + sh.w; v3 = v3 > 0.f ? v3 : alpha*v3;
    uint2 o;
    o.x = pack2(di*v0, di*v1);
    o.y = pack2(di*v2, di*v3);
    if (node < N)
      *(uint2*)(h + (size_t)node * 512 + cb) = o;
  }
}

// ---------------- t = P h : 8-wide unroll ----------------
__global__ __launch_bounds__(256) void k_prop_h(const unsigned int* __restrict__ h2,
                                                const int* __restrict__ csr,
                                                const int* __restrict__ offs, const int* __restrict__ indeg,
                                                const float* __restrict__ dinv,
                                                unsigned int* __restrict__ t2, int N){
  int i = blockIdx.x;
  int c2 = threadIdx.x;
  unsigned int sv = h2[(size_t)i*256 + c2];
  float ax = lo16(sv), ay = hi16(sv);
  int e = offs[i], end = e + indeg[i];
  for (; e + 8 <= end; e += 8){
    int r0 = csr[e], r1 = csr[e+1], r2 = csr[e+2], r3 = csr[e+3];
    int r4 = csr[e+4], r5 = csr[e+5], r6 = csr[e+6], r7 = csr[e+7];
    unsigned int v0 = h2[(size_t)r0*256 + c2], v1 = h2[(size_t)r1*256 + c2];
    unsigned int v2 = h2[(size_t)r2*256 + c2], v3 = h2[(size_t)r3*256 + c2];
    unsigned int v4 = h2[(size_t)r4*256 + c2], v5 = h2[(size_t)r5*256 + c2];
    unsigned int v6 = h2[(size_t)r6*256 + c2], v7 = h2[(size_t)r7*256 + c2];
    ax += lo16(v0)+lo16(v1)+lo16(v2)+lo16(v3)+lo16(v4)+lo16(v5)+lo16(v6)+lo16(v7);
    ay += hi16(v0)+hi16(v1)+hi16(v2)+hi16(v3)+hi16(v4)+hi16(v5)+hi16(v6)+hi16(v7);
  }
  for (; e < end; e++){
    unsigned int v = h2[(size_t)csr[e]*256 + c2];
    ax += lo16(v); ay += hi16(v);
  }
  float di = dinv[i];
  t2[(size_t)i*256 + c2] = pack2(di * ax, di * ay);
}

// ---------------- mm2 fused: out = sum_g mix_g * prelu(BN(t_g @ W2_g + b2_g)) ----------
__global__ __launch_bounds__(256) void k_mm2f(const unsigned short* __restrict__ t,
                                              const unsigned short* __restrict__ Wt,
                                              const float* __restrict__ scale, const float* __restrict__ shiftF,
                                              const float* __restrict__ alpha_p, const float* __restrict__ mixe,
                                              float* __restrict__ out, int N){
  __shared__ float red[4][16][132];   // padded to break bank conflicts
  float alpha = alpha_p[0];
  int wave = threadIdx.x >> 6, lane = threadIdx.x & 63;
  int l16 = lane & 15, quad = lane >> 4;
  int node = blockIdx.x * 16 + l16;
  int nc = node < N ? node : N - 1;

  // softmax mix weight for (node, g=wave)
  float4 me = ((const float4*)mixe)[nc];
  float mx = fmaxf(fmaxf(me.x, me.y), fmaxf(me.z, me.w));
  float e0 = __expf(me.x - mx), e1 = __expf(me.y - mx), e2 = __expf(me.z - mx), e3 = __expf(me.w - mx);
  float inv = 1.f / (e0 + e1 + e2 + e3);
  float wvx = ((wave == 0) ? e0 : (wave == 1) ? e1 : (wave == 2) ? e2 : e3) * inv;

  const unsigned short* inrow = t + (size_t)nc * 512 + wave * 128 + quad * 8;
  bfrag b0 = *(const bfrag*)(inrow);
  bfrag b1 = *(const bfrag*)(inrow + 32);
  bfrag b2 = *(const bfrag*)(inrow + 64);
  bfrag b3 = *(const bfrag*)(inrow + 96);

  #pragma unroll
  for (int ct = 0; ct < 8; ct++){
    int c512 = wave * 128 + ct * 16;           // global col base for scale/shift & weights
    const unsigned short* wrow = Wt + (size_t)(c512 + l16) * 128 + quad * 8;
    bfrag a0 = *(const bfrag*)(wrow);
    bfrag a1 = *(const bfrag*)(wrow + 32);
    bfrag a2 = *(const bfrag*)(wrow + 64);
    bfrag a3 = *(const bfrag*)(wrow + 96);
    ffrag acc = {0.f, 0.f, 0.f, 0.f};
    acc = __builtin_amdgcn_mfma_f32_16x16x32_bf16(a0, b0, acc, 0, 0, 0);
    acc = __builtin_amdgcn_mfma_f32_16x16x32_bf16(a1, b1, acc, 0, 0, 0);
    acc = __builtin_amdgcn_mfma_f32_16x16x32_bf16(a2, b2, acc, 0, 0, 0);
    acc = __builtin_amdgcn_mfma_f32_16x16x32_bf16(a3, b3, acc, 0, 0, 0);
    int cb = c512 + quad * 4;
    float4 sc = *(const float4*)(scale + cb);
    float4 sh = *(const float4*)(shiftF + cb);
    float v0 = acc[0]*sc.x + sh.x; v0 = v0 > 0.f ? v0 : alpha*v0;
    float v1 = acc[1]*sc.y + sh.y; v1 = v1 > 0.f ? v1 : alpha*v1;
    float v2 = acc[2]*sc.z + sh.z; v2 = v2 > 0.f ? v2 : alpha*v2;
    float v3 = acc[3]*sc.w + sh.w; v3 = v3 > 0.f ? v3 : alpha*v3;
    int j = ct * 16 + quad * 4;                // within-group output col
    float4 wr = {wvx*v0, wvx*v1, wvx*v2, wvx*v3};
    *(float4*)&red[wave][l16][j] = wr;
  }
  __syncthreads();
  // reduce the 4 groups and store out (fp32, N x 128)
  int tt = threadIdx.x;
  int nn = tt >> 4, j0 = (tt & 15) * 8;
  int gnode = blockIdx.x * 16 + nn;
  if (gnode < N){
    float4 r0 = {0,0,0,0}, r1 = {0,0,0,0};
    #pragma unroll
    for (int w = 0; w < 4; w++){
      float4 p0 = *(const float4*)&red[w][nn][j0];
      float4 p1 = *(const float4*)&red[w][nn][j0 + 4];
      r0.x += p0.x; r0.y += p0.y; r0.z += p0.z; r0.w += p0.w;
      r1.x += p1.x; r1.y += p1.y; r1.z += p1.z; r1.w += p1.w;
    }
    float* op = out + (size_t)gnode * 128 + j0;
    *(float4*)(op) = r0;
    *(float4*)(op + 4) = r1;
  }
}

extern "C" void kernel_launch(void* const* d_in, const int* in_sizes, int n_in,
                              void* d_out, int out_size, void* d_ws, size_t ws_size,
                              hipStream_t stream) {
  const float* x      = (const float*)d_in[0];
  const int*   ei     = (const int*)d_in[1];
  const float* W1     = (const float*)d_in[2];
  const float* b1     = (const float*)d_in[3];   // cancels analytically
  const float* W2     = (const float*)d_in[4];
  const float* b2     = (const float*)d_in[5];   // cancels analytically
  const float* gamma1 = (const float*)d_in[6];
  const float* beta1  = (const float*)d_in[7];
  const float* gamma2 = (const float*)d_in[8];
  const float* beta2  = (const float*)d_in[9];
  const float* alpha  = (const float*)d_in[10];
  const float* mixe   = (const float*)d_in[11];
  float* out = (float*)d_out;
  (void)b1; (void)b2;

  const int N = in_sizes[0] / 128;
  const int E = in_sizes[1] / 2;
  const int* rowv = ei;
  const int* colv = ei + E;

  char* w = (char*)d_ws;
  size_t off = 0;
  auto take = [&](size_t bytes) -> void* {
    void* p = w + off;
    off = (off + bytes + 255) & ~(size_t)255;
    return p;
  };
  int*   indeg  = (int*)take((size_t)N * 4);
  int*   cursor = (int*)take((size_t)N * 4);
  int*   offs   = (int*)take((size_t)N * 4);
  int*   bsum   = (int*)take(4096);
  float* dinv   = (float*)take((size_t)N * 4);
  // gram region (single memset): G1 | G2 | m1 | m2
  float* G1     = (float*)take(65536);
  float* G2     = (float*)take(262144);
  float* m1     = (float*)take(512);
  float* m2     = (float*)take(2048);
  float* scale1 = (float*)take(2048);
  float* shift1 = (float*)take(2048);
  float* scale2 = (float*)take(2048);
  float* shift2 = (float*)take(2048);
  int*   csr    = (int*)take((size_t)E * 4);
  unsigned short* Wt1 = (unsigned short*)take(512 * 128 * 2);
  unsigned short* Wt2 = (unsigned short*)take(512 * 128 * 2);
  unsigned short* xs = (unsigned short*)take((size_t)N * 128 * 2);
  unsigned short* sb = (unsigned short*)take((size_t)N * 128 * 2);
  unsigned short* h  = (unsigned short*)take((size_t)N * 512 * 2);
  unsigned short* tb = (unsigned short*)take((size_t)N * 512 * 2);

  hipMemsetAsync(indeg, 0, (size_t)N * 4, stream);
  hipMemsetAsync(G1, 0, 65536 + 262144 + 512 + 2048, stream);

  int ebl = (E + 255) / 256;
  int nb  = (N + 255) / 256;
  float invN = 1.0f / (float)N;

  k_deg<<<ebl, 256, 0, stream>>>(colv, indeg, N, E);
  k_blocksum<<<nb, 256, 0, stream>>>(indeg, bsum, N);
  k_scan_bsum<<<1, 1024, 0, stream>>>(bsum, nb);
  k_scan_node<<<nb, 256, 0, stream>>>(indeg, bsum, offs, cursor, dinv, N);
  k_scatter<<<ebl, 256, 0, stream>>>(rowv, colv, cursor, csr, N, E);

  k_wcast<<<512, 256, 0, stream>>>(W1, W2, Wt1, Wt2);
  k_castx<<<512, 256, 0, stream>>>(x, dinv, xs, N * 32);
  k_prop_x<<<(N + 3) / 4, 256, 0, stream>>>((const unsigned int*)xs, csr, offs, indeg, dinv, (unsigned int*)sb, N);

  // stage 1: analytic BN from Gram(s), then fused GEMM->BN->PReLU->dinv -> h
  k_gram<<<dim3(32, 1), 256, 0, stream>>>(sb, 128, 0, G1, m1, N);
  k_bnfit<<<512, 64, 0, stream>>>(W1, gamma1, beta1, G1, 0, m1, 0, scale1, shift1, invN);
  k_mm1f<<<(N + 15) / 16, 256, 0, stream>>>(sb, Wt1, scale1, shift1, alpha, dinv, h, N);

  k_prop_h<<<N, 256, 0, stream>>>((const unsigned int*)h, csr, offs, indeg, dinv, (unsigned int*)tb, N);

  // stage 2: per-group Gram(t), analytic BN, fused GEMM->BN->PReLU->mix->sum -> out
  k_gram<<<dim3(32, 4), 256, 0, stream>>>(tb, 512, 128, G2, m2, N);
  k_bnfit<<<512, 64, 0, stream>>>(W2, gamma2, beta2, G2, 16384, m2, 128, scale2, shift2, invN);
  k_mm2f<<<(N + 15) / 16, 256, 0, stream>>>(tb, Wt2, scale2, shift2, alpha, mixe, out, N);
}